// Round 1
// baseline (283.220 us; speedup 1.0000x reference)
//
#include <hip/hip_runtime.h>
#include <hip/hip_bf16.h>

// Problem constants
#define B_N 16384
#define A_N 32
#define U_N 64
#define S_N 2048
#define E_N 32
#define HYP_N 64
#define H_N 4
#define NREAL 288   // 256 selector-hypernet cols + 32 v-net cols
#define NPADG 320   // GEMM N padded to 320 (20 MFMA col-tiles)

#define H1_STRIDE 312   // shorts per h1 row (624 B, 16B-aligned)
#define TS_STRIDE 260   // floats per tsb row

// workspace byte offsets (16B-aligned)
#define WS_WT    0                         // Wt bf16 [320][2048] = 1310720 B
#define WS_MB    1310720                   // Mb bf16 [H][U][64]  = 32768 B
#define WS_PMAG  (WS_MB + 32768)           // 1343488
#define WS_PENT  (WS_PMAG + 65536)         // 1409024
#define WS_H1    (WS_PENT + 262144)        // 1671168; h1 bf16 [B][312] = 10223616 B

// output layout (floats): head_attend [B,A] | v [B] | mag | ent [H]
#define OUT_V   (B_N * A_N)
#define OUT_MAG (OUT_V + B_N)
#define OUT_ENT (OUT_MAG + 1)

typedef __attribute__((ext_vector_type(8))) short bf16x8_t;
typedef __attribute__((ext_vector_type(4))) float floatx4_t;

#define AS1(p) ((const __attribute__((address_space(1))) void*)(p))
#define AS3(p) ((__attribute__((address_space(3))) void*)(p))

__device__ __forceinline__ unsigned short f2b(float f) {
    union { float f; unsigned u; } v; v.f = f;
    unsigned r = v.u + 0x7FFFu + ((v.u >> 16) & 1u);   // RNE
    return (unsigned short)(r >> 16);
}

// ---------------------------------------------------------------------------
// Pack: Wt bf16 [320][2048] (W^T of [sel_w1 | v_w1 | 0]) and
//       Mb bf16 [H][U][64]: M[h][u][k] = sum_e key_w[h][u][e]*sel_w2[h][k][e]
// ---------------------------------------------------------------------------
__global__ __launch_bounds__(256) void pack_w_kernel(
        const float* __restrict__ sel_w1, const float* __restrict__ v_w1,
        const float* __restrict__ sel_w2, const float* __restrict__ key_w,
        unsigned short* __restrict__ Wt, unsigned short* __restrict__ Mb) {
    int idx = blockIdx.x * 256 + threadIdx.x;
    if (idx < NPADG * S_N) {
        int n = idx >> 11;          // / 2048
        int k = idx & 2047;
        float val = 0.0f;
        if (n < 256) {
            int h = n >> 6, kk = n & 63;
            val = sel_w1[((size_t)h * S_N + k) * HYP_N + kk];
        } else if (n < NREAL) {
            val = v_w1[(size_t)k * E_N + (n - 256)];
        }
        Wt[idx] = f2b(val);
    } else if (idx < NPADG * S_N + H_N * U_N * HYP_N) {
        int j = idx - NPADG * S_N;          // [h][u][k]
        int h = j >> 12, u = (j >> 6) & 63, k = j & 63;
        const float* kw = key_w + ((size_t)h * U_N + u) * E_N;
        const float* w2 = sel_w2 + ((size_t)h * HYP_N + k) * E_N;
        float s = 0.0f;
#pragma unroll
        for (int e = 0; e < E_N; ++e) s = fmaf(kw[e], w2[e], s);
        Mb[j] = f2b(s);
    }
}

// ---------------------------------------------------------------------------
// GEMM kernel: h1 = relu(states @ [sel_w1|v_w1] + bias) -> bf16 global.
// BM=32, BN=320, BK=64; 512 blocks x 512 threads; LDS 44 KB -> 3 blocks/CU.
// A fp32 reg-prefetched one iter ahead by waves 0-3; B via global_load_lds
// w=16; XOR-swizzled LDS (validated ~0 conflicts).
// ---------------------------------------------------------------------------
#define FM_BM 32
#define FM_BK 64
#define NIT   (S_N / FM_BK)   // 32

__global__ __launch_bounds__(512, 6) void gemm_h1_kernel(
        const float* __restrict__ states, const unsigned short* __restrict__ Wt,
        const float* __restrict__ sel_b1, const float* __restrict__ v_b1,
        unsigned short* __restrict__ h1g) {
    // pool: Asm 4096 | Bsm 40960 = 45056 B
    __shared__ __align__(16) char pool[4096 + 40960];
    unsigned short* Asm = (unsigned short*)pool;
    unsigned short* Bsm = (unsigned short*)(pool + 4096);

    const int t = threadIdx.x;
    const int lane = t & 63;
    const int w = t >> 6;               // 0..7
    const int m0 = blockIdx.x * FM_BM;
    const int miw = (w & 1) * 16;       // 2-way M split: 16 rows/wave
    const int nw = (w >> 1) * 80;       // 4-way N split: 5 tiles/wave

    // A staging (threads 0..255 only): thread owns row ar = t>>3, k-octet acl
    const int ar = t >> 3, acl = t & 7;
    const float* ap = states + (size_t)(m0 + ar) * S_N + acl * 8;

    floatx4_t acc[5] = {};
    float4 a0, a1;

    // ---- prologue: A(0) regs -> LDS, B(0) glds, A(1) prefetch ----
    if (t < 256) {
        a0 = *(const float4*)(ap);
        a1 = *(const float4*)(ap + 4);
        int ph = acl ^ (ar & 7);
        uint4 o;
        o.x = (unsigned)f2b(a0.x) | ((unsigned)f2b(a0.y) << 16);
        o.y = (unsigned)f2b(a0.z) | ((unsigned)f2b(a0.w) << 16);
        o.z = (unsigned)f2b(a1.x) | ((unsigned)f2b(a1.y) << 16);
        o.w = (unsigned)f2b(a1.z) | ((unsigned)f2b(a1.w) << 16);
        *(uint4*)(Asm + (size_t)(ar * 8 + ph) * 8) = o;
    }
#pragma unroll
    for (int i = 0; i < 5; ++i) {
        int p = i * 512 + t, n = p >> 3, sl = p & 7;
        int cl = sl ^ (n & 7);
        __builtin_amdgcn_global_load_lds(AS1(Wt + (size_t)n * S_N + cl * 8),
                                         AS3(Bsm + p * 8), 16, 0, 0);
    }
    if (t < 256) {                      // A(1) prefetch
        a0 = *(const float4*)(ap + FM_BK);
        a1 = *(const float4*)(ap + FM_BK + 4);
    }
    __syncthreads();

    // ---- K-loop: 32 iters ----
    for (int it = 0; it < NIT; ++it) {
        // MFMA phase on current tile
#pragma unroll
        for (int s = 0; s < 2; ++s) {       // two K=32 steps
            const int c = s * 4 + (lane >> 4);
            int r = miw + (lane & 15);
            int pha = c ^ (r & 7);
            bf16x8_t afr = *(const bf16x8_t*)(Asm + r * 64 + pha * 8);
#pragma unroll
            for (int nt = 0; nt < 5; ++nt) {
                int n = nw + nt * 16 + (lane & 15);
                int ph = c ^ (n & 7);
                bf16x8_t bfr = *(const bf16x8_t*)(Bsm + n * 64 + ph * 8);
                acc[nt] = __builtin_amdgcn_mfma_f32_16x16x32_bf16(
                    afr, bfr, acc[nt], 0, 0, 0);
            }
        }
        __syncthreads();   // LDS readers done; A prefetch drained
        if (it < NIT - 1) {
            int k0 = (it + 1) * FM_BK;
            if (t < 256) {                  // A(it+1) regs -> LDS
                int ph = acl ^ (ar & 7);
                uint4 o;
                o.x = (unsigned)f2b(a0.x) | ((unsigned)f2b(a0.y) << 16);
                o.y = (unsigned)f2b(a0.z) | ((unsigned)f2b(a0.w) << 16);
                o.z = (unsigned)f2b(a1.x) | ((unsigned)f2b(a1.y) << 16);
                o.w = (unsigned)f2b(a1.z) | ((unsigned)f2b(a1.w) << 16);
                *(uint4*)(Asm + (size_t)(ar * 8 + ph) * 8) = o;
            }
#pragma unroll
            for (int i = 0; i < 5; ++i) {   // B(it+1)
                int p = i * 512 + t, n = p >> 3, sl = p & 7;
                int cl = sl ^ (n & 7);
                __builtin_amdgcn_global_load_lds(
                    AS1(Wt + (size_t)n * S_N + k0 + cl * 8),
                    AS3(Bsm + p * 8), 16, 0, 0);
            }
            if (it < NIT - 2 && t < 256) {  // A(it+2) prefetch
                const float* g = ap + (it + 2) * FM_BK;
                a0 = *(const float4*)(g);
                a1 = *(const float4*)(g + 4);
            }
            __syncthreads();   // staging visible before next MFMA phase
        }
    }

    // ---- bias + relu -> h1 global (bf16). C/D: col=lane&15, row=(lane>>4)*4+rg
    // layout per row: head h at h*72 (k 0..63), v-col j at (j>>3)*72+64+(j&7)
    unsigned short* hrow = h1g + (size_t)m0 * H1_STRIDE;
#pragma unroll
    for (int nt = 0; nt < 5; ++nt) {
        int n = nw + nt * 16 + (lane & 15);
        if (n >= NREAL) continue;
        float bias = (n < 256) ? sel_b1[n] : v_b1[n - 256];
        int slot = (n < 256) ? ((n >> 6) * 72 + (n & 63))
                             : (((n - 256) >> 3) * 72 + 64 + ((n - 256) & 7));
#pragma unroll
        for (int rg = 0; rg < 4; ++rg) {
            int r = miw + (lane >> 4) * 4 + rg;
            float v = acc[nt][rg] + bias;
            hrow[(size_t)r * H1_STRIDE + slot] = f2b(v > 0.0f ? v : 0.0f);
        }
    }
}

// ---------------------------------------------------------------------------
// Attend kernel: 16 rows/block, 256 threads (4 waves), 1024 blocks.
// Phase T: wave w = head w, MFMA t = h1 @ M^T (h1 frags straight from global).
// Phase L: register-lean streaming logits + softmax (no max-sub; fused ent).
// LDS = tsb only (16.6 KB) -> up to 8 blocks/CU.
// ---------------------------------------------------------------------------
#define K2_BM 16

__global__ __launch_bounds__(256, 8) void attend_kernel(
        const float* __restrict__ states, const unsigned short* __restrict__ h1g,
        const unsigned short* __restrict__ Mb,
        const float* __restrict__ v_w2, const float* __restrict__ v_b2,
        float* __restrict__ out, float* __restrict__ pmag, float* __restrict__ pent) {
    __shared__ __align__(16) float tsb[K2_BM * TS_STRIDE];
    const int t = threadIdx.x;
    const int lane = t & 63;
    const int w = t >> 6;               // 0..3 = head
    const int m0 = blockIdx.x * K2_BM;

    // ---- phase T: wave w -> head h = w, rows 0..15; MFMA ----
    {
        const int h = w;
        const unsigned short* hbase =
            h1g + (size_t)(m0 + (lane & 15)) * H1_STRIDE + h * 72;
        floatx4_t tacc[4] = {};
#pragma unroll
        for (int s = 0; s < 2; ++s) {
            int k0 = s * 32 + (lane >> 4) * 8;
            bf16x8_t afr = *(const bf16x8_t*)(hbase + k0);
#pragma unroll
            for (int ut = 0; ut < 4; ++ut) {
                int u = ut * 16 + (lane & 15);
                bf16x8_t bfr = *(const bf16x8_t*)(Mb + ((size_t)(h * U_N + u) * 64) + k0);
                tacc[ut] = __builtin_amdgcn_mfma_f32_16x16x32_bf16(
                    afr, bfr, tacc[ut], 0, 0, 0);
            }
        }
#pragma unroll
        for (int ut = 0; ut < 4; ++ut)
#pragma unroll
            for (int rg = 0; rg < 4; ++rg) {
                int r = (lane >> 4) * 4 + rg;
                int u = ut * 16 + (lane & 15);
                tsb[r * TS_STRIDE + h * U_N + u] = tacc[ut][rg];
            }
    }
    __syncthreads();

    // ---- phase L: wave w handles rows w*4 .. w*4+3 ----
    const int a = lane & 31, uh = lane >> 5;
    for (int rr = 0; rr < 4; ++rr) {
        const int r = w * 4 + rr;
        const int b = m0 + r;
        const float* up = states + (size_t)b * S_N + a * 64 + uh * 32;
        const float* tp = &tsb[r * TS_STRIDE + uh * 32];
        float pl[4] = {0.0f, 0.0f, 0.0f, 0.0f};
        // 2-deep float4 pipeline; working set ~20 regs (no bulk arrays)
        float4 c0 = ((const float4*)up)[0];
        float4 c1 = ((const float4*)up)[1];
#pragma unroll
        for (int i = 0; i < 8; ++i) {
            float4 s4 = c0;
            c0 = c1;
            if (i < 6) c1 = ((const float4*)up)[i + 2];
#pragma unroll
            for (int h = 0; h < 4; ++h) {
                float4 t4 = *(const float4*)(tp + h * U_N + i * 4);
                pl[h] = fmaf(s4.x, t4.x, pl[h]);
                pl[h] = fmaf(s4.y, t4.y, pl[h]);
                pl[h] = fmaf(s4.z, t4.z, pl[h]);
                pl[h] = fmaf(s4.w, t4.w, pl[h]);
            }
        }
#pragma unroll
        for (int h = 0; h < 4; ++h)
            pl[h] += __shfl_xor(pl[h], 32, 64);   // combine u-halves

        float mg = pl[0]*pl[0] + pl[1]*pl[1] + pl[2]*pl[2] + pl[3]*pl[3];
#pragma unroll
        for (int o = 16; o > 0; o >>= 1) mg += __shfl_xor(mg, o, 32);

        // softmax without max-subtraction (|x| <~ 2, range-safe) + fused entropy:
        //   ent = sum_a wv*log(wv) = (sum_a p*x)/den - log(den)
        float hatt = 0.0f;
        float entv[4];
#pragma unroll
        for (int h = 0; h < 4; ++h) {
            float x = pl[h] * 0.17677669529663687f;   // 1/sqrt(E=32)
            float p = __expf(x);
            float den = p, px = p * x;
#pragma unroll
            for (int o = 16; o > 0; o >>= 1) {
                den += __shfl_xor(den, o, 32);
                px  += __shfl_xor(px,  o, 32);
            }
            float inv = 1.0f / den;
            hatt = fmaf(p, inv, hatt);
            entv[h] = px * inv - __logf(den);
        }

        if (uh == 0) {
            out[(size_t)b * A_N + a] = hatt;
            // v head: h1 v-col a read back from global (bf16 -> f32)
            unsigned hv = h1g[(size_t)b * H1_STRIDE + (a >> 3) * 72 + 64 + (a & 7)];
            union { unsigned u; float f; } cv; cv.u = hv << 16;
            float pv = cv.f * v_w2[a];
#pragma unroll
            for (int o = 16; o > 0; o >>= 1) pv += __shfl_xor(pv, o, 32);
            if (a == 0) {
                out[OUT_V + b] = pv + v_b2[0];
                pmag[b] = mg;
#pragma unroll
                for (int h = 0; h < 4; ++h) pent[(size_t)h * B_N + b] = entv[h];
            }
        }
    }
}

// ---------------------------------------------------------------------------
// Deterministic final reduction
// ---------------------------------------------------------------------------
__global__ __launch_bounds__(256) void finalize_kernel(
        const float* __restrict__ pmag, const float* __restrict__ pent,
        float* __restrict__ out) {
    int which = blockIdx.x;   // 0..4
    const float* src = (which == 0) ? pmag : (pent + (size_t)(which - 1) * B_N);
    float s = 0.0f;
    for (int i = threadIdx.x; i < B_N; i += 256) s += src[i];
#pragma unroll
    for (int o = 32; o > 0; o >>= 1) s += __shfl_xor(s, o, 64);
    __shared__ float red[4];
    if ((threadIdx.x & 63) == 0) red[threadIdx.x >> 6] = s;
    __syncthreads();
    if (threadIdx.x == 0) {
        float tot = red[0] + red[1] + red[2] + red[3];
        if (which == 0) out[OUT_MAG] = 1e-3f * tot / (float)(B_N * A_N);
        else out[OUT_ENT + which - 1] = -tot / (float)B_N;
    }
}

// ---------------------------------------------------------------------------
extern "C" void kernel_launch(void* const* d_in, const int* in_sizes, int n_in,
                              void* d_out, int out_size, void* d_ws, size_t ws_size,
                              hipStream_t stream) {
    const float* states = (const float*)d_in[1];
    const float* sel_w1 = (const float*)d_in[2];
    const float* sel_b1 = (const float*)d_in[3];
    const float* sel_w2 = (const float*)d_in[4];
    const float* key_w  = (const float*)d_in[5];
    const float* v_w1   = (const float*)d_in[6];
    const float* v_b1   = (const float*)d_in[7];
    const float* v_w2   = (const float*)d_in[8];
    const float* v_b2   = (const float*)d_in[9];
    float* out = (float*)d_out;
    char* wsb  = (char*)d_ws;

    unsigned short* Wt  = (unsigned short*)(wsb + WS_WT);
    unsigned short* Mb  = (unsigned short*)(wsb + WS_MB);
    float* pmag         = (float*)(wsb + WS_PMAG);
    float* pent         = (float*)(wsb + WS_PENT);
    unsigned short* h1g = (unsigned short*)(wsb + WS_H1);

    pack_w_kernel<<<dim3((NPADG * S_N + H_N * U_N * HYP_N + 255) / 256),
                    dim3(256), 0, stream>>>(sel_w1, v_w1, sel_w2, key_w, Wt, Mb);
    gemm_h1_kernel<<<dim3(B_N / FM_BM), dim3(512), 0, stream>>>(
        states, Wt, sel_b1, v_b1, h1g);
    attend_kernel<<<dim3(B_N / K2_BM), dim3(256), 0, stream>>>(
        states, h1g, Mb, v_w2, v_b2, out, pmag, pent);
    finalize_kernel<<<dim3(5), dim3(256), 0, stream>>>(pmag, pent, out);
}